// Round 5
// baseline (686.312 us; speedup 1.0000x reference)
//
#include <hip/hip_runtime.h>
#include <hip/hip_bf16.h>
#include <cstdint>

// Transformer block: LN1 -> QKV GEMM -> attention -> proj(+res) -> LN2 -> MLP(+res)
// GEMM: 256-wide tiles, BK=64, 8 waves, double-buffered LDS, register-held operand
// fragments (each LDS byte read once per K-tile), 1 barrier per phase, counted vmcnt.

typedef __bf16 bf16;
typedef bf16 bf16x8 __attribute__((ext_vector_type(8)));
typedef float f32x4 __attribute__((ext_vector_type(4)));
typedef uint32_t u32;

__device__ __forceinline__ f32x4 mfma16(bf16x8 a, bf16x8 b, f32x4 c){
  return __builtin_amdgcn_mfma_f32_16x16x32_bf16(a, b, c, 0, 0, 0);
}

// global -> LDS direct copy, 16B per lane; LDS dest wave-uniform base + lane*16.
__device__ __forceinline__ void gload16(const void* g, const void* l){
  __builtin_amdgcn_global_load_lds(
      (__attribute__((address_space(1))) u32*)(uintptr_t)g,
      (__attribute__((address_space(3))) u32*)(u32)(uintptr_t)l,
      16, 0, 0);
}

// ---------------- weight transpose-cast: W[K,N] f32 -> Wt[N,K] bf16 ----------------
__global__ __launch_bounds__(256)
void transpose_cast(const float* __restrict__ W, bf16* __restrict__ Wt, int K, int N)
{
  __shared__ float t[64][65];
  int n0 = blockIdx.x * 64, k0 = blockIdx.y * 64;
  int tid = threadIdx.x;
  int c = tid & 63, r4 = tid >> 6;
#pragma unroll
  for (int i = 0; i < 16; ++i){
    int r = r4 * 16 + i;
    t[r][c] = W[(size_t)(k0 + r) * N + n0 + c];
  }
  __syncthreads();
#pragma unroll
  for (int i = 0; i < 16; ++i){
    int r = r4 * 16 + i;
    Wt[(size_t)(n0 + r) * K + k0 + c] = (bf16)t[c][r];
  }
}

// ---------------- LayerNorm: f32 [rows,768] -> bf16, one block per row ----------------
__global__ __launch_bounds__(256)
void ln_kernel(const float* __restrict__ x, const float* __restrict__ g,
               const float* __restrict__ b, bf16* __restrict__ out)
{
  int row = blockIdx.x;
  int tid = threadIdx.x;
  const float* xr = x + (size_t)row * 768;
  float v0 = xr[tid], v1 = xr[tid + 256], v2 = xr[tid + 512];
  float s = v0 + v1 + v2;
  float ss = v0*v0 + v1*v1 + v2*v2;
#pragma unroll
  for (int m = 1; m < 64; m <<= 1){
    s  += __shfl_xor(s,  m, 64);
    ss += __shfl_xor(ss, m, 64);
  }
  __shared__ float red[8];
  int w = tid >> 6, l = tid & 63;
  if (l == 0){ red[w] = s; red[4 + w] = ss; }
  __syncthreads();
  s  = red[0] + red[1] + red[2] + red[3];
  ss = red[4] + red[5] + red[6] + red[7];
  float mu  = s * (1.0f / 768.0f);
  float var = ss * (1.0f / 768.0f) - mu * mu;
  float rs  = rsqrtf(var + 1e-5f);
  bf16* o = out + (size_t)row * 768;
  o[tid]       = (bf16)((v0 - mu) * rs * g[tid]       + b[tid]);
  o[tid + 256] = (bf16)((v1 - mu) * rs * g[tid + 256] + b[tid + 256]);
  o[tid + 512] = (bf16)((v2 - mu) * rs * g[tid + 512] + b[tid + 512]);
}

// ---------------- GEMM: C[M,N] = A[M,K](bf16) * Bt[N,K](bf16)^T ----------------
// BM = BMQ*64 (BMQ=4 -> 256x256 tile, BMQ=2 -> 128x256), BN=256, BK=64.
// 8 waves as 2x4; per-wave output (BM/2)x64. Each LDS byte is ds_read ONCE per
// K-tile: both B halves + one A half held in registers. One barrier per phase.
// EPI: 0 = bf16 store, 1 = bf16 gelu(x+bias), 2 = f32 x+bias+res.
template<int EPI, int BMQ>
__global__ __launch_bounds__(512, 2)
void gemm256(const bf16* __restrict__ A, const bf16* __restrict__ Bt,
             const float* __restrict__ bias, const float* __restrict__ res,
             void* __restrict__ Cout, int M, int N, int K)
{
  constexpr int BM   = BMQ * 64;
  constexpr int MHN  = BMQ / 2;            // A halves per wave (2 or 1)
  constexpr int ABUF = BM * 64;            // A elems per buffer
  constexpr int BUFE = ABUF + 16384;       // + B (256x64)
  extern __shared__ bf16 lds[];            // 2 * BUFE elems
  const int tid = threadIdx.x;
  const int w = tid >> 6, l = tid & 63;
  const int lr = l & 15, lg = l >> 4;
  const int wr = w >> 2, wc = w & 3;       // 2 x 4 wave grid
  const int nbm = M / BM, nbn = N >> 8;
  const int nwg = nbm * nbn;
  const int cpx = nwg >> 3;                // grids %8==0 -> bijective
  const int bid = (int)blockIdx.x;
  const int sw  = (bid & 7) * cpx + (bid >> 3);
  const int bn = sw % nbn, bm = sw / nbn;  // bn fast: co-resident blocks share A
  const int rowA0 = bm * BM, colB0 = bn << 8;

  f32x4 acc[MHN * 4][4];
#pragma unroll
  for (int i = 0; i < MHN * 4; ++i)
#pragma unroll
    for (int j = 0; j < 4; ++j) acc[i][j] = f32x4{0.f, 0.f, 0.f, 0.f};

  // staging: linear LDS dest, inverse-swizzled global source (granule ^= row&7).
  const int srow = l >> 3;
  const int sg   = (l & 7) ^ srow;

  bf16* nbuf = lds;          // stage destination buffer (tile being prefetched)
  int   ktn  = 0;            // k offset of tile being prefetched

  auto stA = [&](int q){     // stage 64-row A quarter q
    bf16* dst = nbuf + q * 4096 + w * 512;
    int row = q * 64 + w * 8 + srow;
    gload16(A + (size_t)(rowA0 + row) * K + ktn + sg * 8, dst);
  };
  auto stB = [&](int nh, int j){   // stage B half nh, part j (32 rows)
    int hh = j * 8 + w;
    int row0 = (hh >> 2) * 64 + nh * 32 + (hh & 3) * 8;
    bf16* dst = nbuf + ABUF + row0 * 64;
    gload16(Bt + (size_t)(colB0 + row0 + srow) * K + ktn + sg * 8, dst);
  };

  const int NT = K >> 6;

  // prologue: stage tile 0 in queue order matching consumption
  if (BMQ == 4){
    stA(0); stA(2); stB(0,0); stB(0,1); stB(1,0); stB(1,1); stA(1); stA(3);
    asm volatile("s_waitcnt vmcnt(4)" ::: "memory");
  } else {
    stA(0); stA(1); stB(0,0); stB(0,1); stB(1,0); stB(1,1);
    asm volatile("s_waitcnt vmcnt(2)" ::: "memory");
  }
  __builtin_amdgcn_s_barrier();

  bf16x8 af[4][2];        // current A half
  bf16x8 bfr[2][2][2];    // both B halves, live across the K-tile

#define RDA(MH)                                                               \
  _Pragma("unroll")                                                           \
  for (int fr = 0; fr < 4; ++fr)                                              \
    _Pragma("unroll")                                                         \
    for (int kk = 0; kk < 2; ++kk){                                           \
      int row = wr * (BM / 2) + (MH) * 64 + fr * 16 + lr;                     \
      af[fr][kk] = *(const bf16x8*)&Abuf[row * 64 +                           \
                     (((kk * 4 + lg) ^ (lr & 7)) << 3)];                      \
    }
#define RDB(NH)                                                               \
  _Pragma("unroll")                                                           \
  for (int fc = 0; fc < 2; ++fc)                                              \
    _Pragma("unroll")                                                         \
    for (int kk = 0; kk < 2; ++kk){                                           \
      int row = wc * 64 + (NH) * 32 + fc * 16 + lr;                           \
      bfr[NH][fc][kk] = *(const bf16x8*)&Bbuf[row * 64 +                      \
                     (((kk * 4 + lg) ^ (lr & 7)) << 3)];                      \
    }
#define MM(MH, NH)                                                            \
  __builtin_amdgcn_s_setprio(1);                                              \
  _Pragma("unroll")                                                           \
  for (int fr = 0; fr < 4; ++fr)                                              \
    _Pragma("unroll")                                                         \
    for (int fc = 0; fc < 2; ++fc)                                            \
      _Pragma("unroll")                                                       \
      for (int kk = 0; kk < 2; ++kk)                                          \
        acc[(MH) * 4 + fr][(NH) * 2 + fc] =                                   \
            mfma16(af[fr][kk], bfr[NH][fc][kk], acc[(MH) * 4 + fr][(NH) * 2 + fc]); \
  __builtin_amdgcn_s_setprio(0);

  for (int T = 0; T < NT; ++T){
    const bf16* Abuf = lds + (size_t)(T & 1) * BUFE;
    const bf16* Bbuf = Abuf + ABUF;
    nbuf = lds + (size_t)((T + 1) & 1) * BUFE;
    ktn  = (T + 1) << 6;
    const bool more = (T + 1 < NT);

    // phase 0: read A-half0 + B-half0
    RDA(0); RDB(0);
    if (BMQ == 4){ if (more){ stA(0); stA(2); }
                   if (more) asm volatile("s_waitcnt vmcnt(4)" ::: "memory");
                   else      asm volatile("s_waitcnt vmcnt(0)" ::: "memory"); }
    else         { if (more){ stA(0); stA(1); stB(0,0); }
                   if (more) asm volatile("s_waitcnt vmcnt(3)" ::: "memory");
                   else      asm volatile("s_waitcnt vmcnt(0)" ::: "memory"); }
    MM(0, 0);
    __builtin_amdgcn_s_barrier();

    // phase 1: read B-half1 (A half stays in regs)
    RDB(1);
    if (BMQ == 4){ if (more){ stB(0,0); stB(0,1); }
                   if (more) asm volatile("s_waitcnt vmcnt(4)" ::: "memory");
                   else      asm volatile("s_waitcnt vmcnt(0)" ::: "memory"); }
    else         { if (more){ stB(0,1); stB(1,0); stB(1,1); }
                   if (more) asm volatile("s_waitcnt vmcnt(2)" ::: "memory");
                   else      asm volatile("s_waitcnt vmcnt(0)" ::: "memory"); }
    MM(0, 1);
    __builtin_amdgcn_s_barrier();

    if (BMQ == 4){
      // phase 2: read A-half1 (B halves stay in regs)
      RDA(1);
      if (more){ stB(1,0); stB(1,1); }
      if (more) asm volatile("s_waitcnt vmcnt(4)" ::: "memory");
      else      asm volatile("s_waitcnt vmcnt(0)" ::: "memory");
      MM(1, 0);
      __builtin_amdgcn_s_barrier();

      // phase 3: no reads
      if (more){ stA(1); stA(3); }
      if (more) asm volatile("s_waitcnt vmcnt(4)" ::: "memory");
      else      asm volatile("s_waitcnt vmcnt(0)" ::: "memory");
      MM(1, 1);
      __builtin_amdgcn_s_barrier();
    }
  }
#undef RDA
#undef RDB
#undef MM

  // epilogue: acc[mi][ni], mi = MH*4+fr, ni = NH*2+fc
  const size_t crow = (size_t)rowA0 + wr * (BM / 2);
  const size_t ccol = (size_t)colB0 + wc * 64;
#pragma unroll
  for (int mi = 0; mi < MHN * 4; ++mi){
#pragma unroll
    for (int ni = 0; ni < 4; ++ni){
      size_t r0 = crow + (mi >> 2) * 64 + (mi & 3) * 16 + lg * 4;
      size_t c  = ccol + (ni >> 1) * 32 + (ni & 1) * 16 + lr;
#pragma unroll
      for (int i = 0; i < 4; ++i){
        size_t r = r0 + i;
        float v = acc[mi][ni][i];
        if (EPI == 0){
          ((bf16*)Cout)[r * (size_t)N + c] = (bf16)v;
        } else if (EPI == 1){
          v += bias[c];
          v = 0.5f * v * (1.0f + erff(v * 0.70710678118654752f));
          ((bf16*)Cout)[r * (size_t)N + c] = (bf16)v;
        } else {
          v += bias[c] + res[r * (size_t)N + c];
          ((float*)Cout)[r * (size_t)N + c] = v;
        }
      }
    }
  }
}

// ---------------- Flash attention: qkv bf16 [16384,2304] -> y bf16 [16384,768] ----------------
__global__ __launch_bounds__(256)
void attn_kernel(const bf16* __restrict__ qkv, bf16* __restrict__ y)
{
  int bid = blockIdx.x;
  int qt  = bid & 7;
  int bsh = bid >> 3;
  int h = bsh % 12;
  int R = bsh / 12;
  size_t rowbase = (size_t)R * 512;
  int tid = threadIdx.x, w = tid >> 6, l = tid & 63;
  int lr = l & 15, lg = l >> 4;

  __shared__ bf16 Kl[64 * 64];
  __shared__ bf16 Vt[64 * 64];
  __shared__ bf16 Pl[4][16 * 64];

  int q0 = qt * 64 + w * 16;
  bf16x8 qf[2];
#pragma unroll
  for (int ks = 0; ks < 2; ++ks)
    qf[ks] = *(const bf16x8*)&qkv[(rowbase + q0 + lr) * 2304 + h * 64 + ks * 32 + lg * 8];

  float mi[4], li[4];
  f32x4 oa[4];
#pragma unroll
  for (int i = 0; i < 4; ++i){ mi[i] = -1e30f; li[i] = 0.f; }
#pragma unroll
  for (int dt = 0; dt < 4; ++dt) oa[dt] = f32x4{0.f, 0.f, 0.f, 0.f};

  for (int c = 0; c < 8; ++c){
    __syncthreads();
    size_t tokbase = rowbase + c * 64;
#pragma unroll
    for (int it = 0; it < 2; ++it){
      int idx = it * 256 + tid;
      int t  = idx >> 3;
      int c8 = idx & 7;
      bf16x8 kv = *(const bf16x8*)&qkv[(tokbase + t) * 2304 + 768 + h * 64 + c8 * 8];
      *(bf16x8*)&Kl[t * 64 + ((c8 ^ (t & 7)) * 8)] = kv;
      bf16x8 vv = *(const bf16x8*)&qkv[(tokbase + t) * 2304 + 1536 + h * 64 + c8 * 8];
#pragma unroll
      for (int j = 0; j < 8; ++j){
        int d = c8 * 8 + j;
        Vt[d * 64 + (((t >> 3) ^ (d & 7)) * 8) + (t & 7)] = vv[j];
      }
    }
    __syncthreads();

    f32x4 s[4];
#pragma unroll
    for (int tt = 0; tt < 4; ++tt){
      f32x4 a = f32x4{0.f, 0.f, 0.f, 0.f};
#pragma unroll
      for (int ks = 0; ks < 2; ++ks){
        int row = tt * 16 + lr;
        int c8 = ks * 4 + lg;
        bf16x8 kf = *(const bf16x8*)&Kl[row * 64 + ((c8 ^ (row & 7)) * 8)];
        a = mfma16(qf[ks], kf, a);
      }
      s[tt] = a * 0.125f;
    }

    float pr[4][4];
#pragma unroll
    for (int i = 0; i < 4; ++i){
      float rm = fmaxf(fmaxf(s[0][i], s[1][i]), fmaxf(s[2][i], s[3][i]));
#pragma unroll
      for (int mm = 1; mm < 16; mm <<= 1) rm = fmaxf(rm, __shfl_xor(rm, mm, 64));
      float mn = fmaxf(mi[i], rm);
      float corr = __expf(mi[i] - mn);
      float rs = 0.f;
#pragma unroll
      for (int tt = 0; tt < 4; ++tt){
        float p = __expf(s[tt][i] - mn);
        pr[tt][i] = p;
        rs += p;
      }
#pragma unroll
      for (int mm = 1; mm < 16; mm <<= 1) rs += __shfl_xor(rs, mm, 64);
      li[i] = li[i] * corr + rs;
#pragma unroll
      for (int dt = 0; dt < 4; ++dt) oa[dt][i] *= corr;
      mi[i] = mn;
    }

#pragma unroll
    for (int i = 0; i < 4; ++i){
      int qr = lg * 4 + i;
#pragma unroll
      for (int tt = 0; tt < 4; ++tt){
        int tok = tt * 16 + lr;
        Pl[w][qr * 64 + (((tok >> 3) ^ (qr & 7)) * 8) + (tok & 7)] = (bf16)pr[tt][i];
      }
    }
    __syncthreads();

#pragma unroll
    for (int ks = 0; ks < 2; ++ks){
      bf16x8 pf = *(const bf16x8*)&Pl[w][lr * 64 + (((ks * 4 + lg) ^ (lr & 7)) * 8)];
#pragma unroll
      for (int dt = 0; dt < 4; ++dt){
        int row = dt * 16 + lr;
        int c8 = ks * 4 + lg;
        bf16x8 vf = *(const bf16x8*)&Vt[row * 64 + ((c8 ^ (row & 7)) * 8)];
        oa[dt] = mfma16(pf, vf, oa[dt]);
      }
    }
  }

#pragma unroll
  for (int i = 0; i < 4; ++i){
    float inv = 1.0f / li[i];
    size_t r = rowbase + q0 + lg * 4 + i;
#pragma unroll
    for (int dt = 0; dt < 4; ++dt)
      y[r * 768 + h * 64 + dt * 16 + lr] = (bf16)(oa[dt][i] * inv);
  }
}

// ---------------- launcher ----------------
extern "C" void kernel_launch(void* const* d_in, const int* in_sizes, int n_in,
                              void* d_out, int out_size, void* d_ws, size_t ws_size,
                              hipStream_t stream)
{
  (void)in_sizes; (void)n_in; (void)out_size; (void)ws_size;
  const float* x    = (const float*)d_in[0];
  const float* g1   = (const float*)d_in[1];
  const float* b1   = (const float*)d_in[2];
  const float* Wqkv = (const float*)d_in[3];
  const float* Wp   = (const float*)d_in[4];
  const float* bp   = (const float*)d_in[5];
  const float* g2   = (const float*)d_in[6];
  const float* b2   = (const float*)d_in[7];
  const float* W1   = (const float*)d_in[8];
  const float* bm1  = (const float*)d_in[9];
  const float* W2   = (const float*)d_in[10];
  const float* bm2  = (const float*)d_in[11];
  float* out = (float*)d_out;

  hipFuncSetAttribute((const void*)gemm256<0,4>, hipFuncAttributeMaxDynamicSharedMemorySize, 131072);
  hipFuncSetAttribute((const void*)gemm256<1,4>, hipFuncAttributeMaxDynamicSharedMemorySize, 131072);
  hipFuncSetAttribute((const void*)gemm256<2,2>, hipFuncAttributeMaxDynamicSharedMemorySize, 98304);

  // ---- lifetime-aliased workspace layout (~140 MB peak) ----
  char* ws = (char*)d_ws;
  size_t off = 0;
  auto alloc = [&](size_t nbytes) -> void* {
    void* p = ws + off;
    off += (nbytes + 255) & ~(size_t)255;
    return p;
  };
  bf16* WqkvT = (bf16*)alloc((size_t)2304 * 768 * 2);
  bf16* WpT   = (bf16*)alloc((size_t)768 * 768 * 2);
  bf16* W1T   = (bf16*)alloc((size_t)3072 * 768 * 2);
  bf16* W2T   = (bf16*)alloc((size_t)768 * 3072 * 2);
  char* R1 = (char*)alloc((size_t)16384 * 768 * 2);
  char* R2 = (char*)alloc((size_t)16384 * 3072 * 2);
  bf16* h   = (bf16*)R1;
  bf16* yb  = (bf16*)R1;
  bf16* h2  = (bf16*)R1;
  bf16* qkv = (bf16*)R2;
  bf16* m1  = (bf16*)R2;
  float* x2 = out;

  transpose_cast<<<dim3(36, 12), dim3(256), 0, stream>>>(Wqkv, WqkvT, 768, 2304);
  transpose_cast<<<dim3(12, 12), dim3(256), 0, stream>>>(Wp,   WpT,   768, 768);
  transpose_cast<<<dim3(48, 12), dim3(256), 0, stream>>>(W1,   W1T,   768, 3072);
  transpose_cast<<<dim3(12, 48), dim3(256), 0, stream>>>(W2,   W2T,   3072, 768);

  // LN1: x -> h (bf16)
  ln_kernel<<<dim3(16384), dim3(256), 0, stream>>>(x, g1, b1, h);
  // QKV: 64 x 9 = 576 blocks
  gemm256<0,4><<<dim3(576), dim3(512), 131072, stream>>>(h, WqkvT, nullptr, nullptr,
                                                         (void*)qkv, 16384, 2304, 768);
  // attention
  attn_kernel<<<dim3(3072), dim3(256), 0, stream>>>(qkv, yb);
  // proj + bias + residual(x) -> x2 (f32, in d_out); 128 x 3 = 384 blocks
  gemm256<2,2><<<dim3(384), dim3(512), 98304, stream>>>(yb, WpT, bp, x,
                                                        (void*)x2, 16384, 768, 768);
  // LN2
  ln_kernel<<<dim3(16384), dim3(256), 0, stream>>>(x2, g2, b2, h2);
  // MLP1 + bias + exact gelu; 64 x 12 = 768 blocks
  gemm256<1,4><<<dim3(768), dim3(512), 131072, stream>>>(h2, W1T, bm1, nullptr,
                                                         (void*)m1, 16384, 3072, 768);
  // MLP2 + bias + residual(x2) -> out; 128 x 3 = 384 blocks
  gemm256<2,2><<<dim3(384), dim3(512), 98304, stream>>>(m1, W2T, bm2, x2,
                                                        (void*)out, 16384, 768, 3072);
}

// Round 6
// 613.890 us; speedup vs baseline: 1.1180x; 1.1180x over previous
//
#include <hip/hip_runtime.h>
#include <hip/hip_bf16.h>
#include <cstdint>

// Transformer block: LN1 -> QKV GEMM -> attention -> proj(+res) -> LN2 -> MLP(+res)
// GEMM: 256-wide tiles, BK=64, 8 waves, double-buffered LDS. Tile T+1 staged in
// full at the TOP of tile T (max vmcnt window); no mid-tile barriers; single
// vmcnt(0)+s_barrier per K-tile. Each LDS byte ds_read once per K-tile.

typedef __bf16 bf16;
typedef bf16 bf16x8 __attribute__((ext_vector_type(8)));
typedef float f32x4 __attribute__((ext_vector_type(4)));
typedef uint32_t u32;

__device__ __forceinline__ f32x4 mfma16(bf16x8 a, bf16x8 b, f32x4 c){
  return __builtin_amdgcn_mfma_f32_16x16x32_bf16(a, b, c, 0, 0, 0);
}

// global -> LDS direct copy, 16B per lane; LDS dest wave-uniform base + lane*16.
__device__ __forceinline__ void gload16(const void* g, const void* l){
  __builtin_amdgcn_global_load_lds(
      (__attribute__((address_space(1))) u32*)(uintptr_t)g,
      (__attribute__((address_space(3))) u32*)(u32)(uintptr_t)l,
      16, 0, 0);
}

// ---------------- weight transpose-cast: W[K,N] f32 -> Wt[N,K] bf16 ----------------
__global__ __launch_bounds__(256)
void transpose_cast(const float* __restrict__ W, bf16* __restrict__ Wt, int K, int N)
{
  __shared__ float t[64][65];
  int n0 = blockIdx.x * 64, k0 = blockIdx.y * 64;
  int tid = threadIdx.x;
  int c = tid & 63, r4 = tid >> 6;
#pragma unroll
  for (int i = 0; i < 16; ++i){
    int r = r4 * 16 + i;
    t[r][c] = W[(size_t)(k0 + r) * N + n0 + c];
  }
  __syncthreads();
#pragma unroll
  for (int i = 0; i < 16; ++i){
    int r = r4 * 16 + i;
    Wt[(size_t)(n0 + r) * K + k0 + c] = (bf16)t[c][r];
  }
}

// ---------------- LayerNorm: f32 [rows,768] -> bf16, one block per row ----------------
__global__ __launch_bounds__(256)
void ln_kernel(const float* __restrict__ x, const float* __restrict__ g,
               const float* __restrict__ b, bf16* __restrict__ out)
{
  int row = blockIdx.x;
  int tid = threadIdx.x;
  const float* xr = x + (size_t)row * 768;
  float v0 = xr[tid], v1 = xr[tid + 256], v2 = xr[tid + 512];
  float s = v0 + v1 + v2;
  float ss = v0*v0 + v1*v1 + v2*v2;
#pragma unroll
  for (int m = 1; m < 64; m <<= 1){
    s  += __shfl_xor(s,  m, 64);
    ss += __shfl_xor(ss, m, 64);
  }
  __shared__ float red[8];
  int w = tid >> 6, l = tid & 63;
  if (l == 0){ red[w] = s; red[4 + w] = ss; }
  __syncthreads();
  s  = red[0] + red[1] + red[2] + red[3];
  ss = red[4] + red[5] + red[6] + red[7];
  float mu  = s * (1.0f / 768.0f);
  float var = ss * (1.0f / 768.0f) - mu * mu;
  float rs  = rsqrtf(var + 1e-5f);
  bf16* o = out + (size_t)row * 768;
  o[tid]       = (bf16)((v0 - mu) * rs * g[tid]       + b[tid]);
  o[tid + 256] = (bf16)((v1 - mu) * rs * g[tid + 256] + b[tid + 256]);
  o[tid + 512] = (bf16)((v2 - mu) * rs * g[tid + 512] + b[tid + 512]);
}

// ---------------- GEMM: C[M,N] = A[M,K](bf16) * Bt[N,K](bf16)^T ----------------
// BM = BMQ*64 (BMQ=4 -> 256x256 tile, BMQ=2 -> 128x256), BN=256, BK=64.
// 8 waves as 2x4; per-wave output (BM/2)x64.
// EPI: 0 = bf16 store, 1 = bf16 gelu(x+bias), 2 = f32 x+bias+res.
template<int EPI, int BMQ>
__global__ __launch_bounds__(512, 2)
void gemm256(const bf16* __restrict__ A, const bf16* __restrict__ Bt,
             const float* __restrict__ bias, const float* __restrict__ res,
             void* __restrict__ Cout, int M, int N, int K)
{
  constexpr int BM   = BMQ * 64;
  constexpr int MHN  = BMQ / 2;            // A halves per wave (2 or 1)
  constexpr int ABUF = BM * 64;            // A elems per buffer
  constexpr int BUFE = ABUF + 16384;       // + B (256x64)
  extern __shared__ bf16 lds[];            // 2 * BUFE elems
  const int tid = threadIdx.x;
  const int w = tid >> 6, l = tid & 63;
  const int lr = l & 15, lg = l >> 4;
  const int wr = w >> 2, wc = w & 3;       // 2 x 4 wave grid
  const int nbm = M / BM, nbn = N >> 8;
  const int nwg = nbm * nbn;
  const int cpx = nwg >> 3;                // grids %8==0 -> bijective
  const int bid = (int)blockIdx.x;
  const int sw  = (bid & 7) * cpx + (bid >> 3);
  const int bn = sw % nbn, bm = sw / nbn;  // bn fast: co-resident blocks share A
  const int rowA0 = bm * BM, colB0 = bn << 8;

  f32x4 acc[MHN * 4][4];
#pragma unroll
  for (int i = 0; i < MHN * 4; ++i)
#pragma unroll
    for (int j = 0; j < 4; ++j) acc[i][j] = f32x4{0.f, 0.f, 0.f, 0.f};

  // staging: linear LDS dest, inverse-swizzled global source (granule ^= row&7).
  const int srow = l >> 3;
  const int sg   = (l & 7) ^ srow;

  bf16* nbuf = lds;          // stage destination buffer (tile being prefetched)
  int   ktn  = 0;            // k offset of tile being prefetched

  auto stA = [&](int q){     // stage 64-row A quarter q
    bf16* dst = nbuf + q * 4096 + w * 512;
    int row = q * 64 + w * 8 + srow;
    gload16(A + (size_t)(rowA0 + row) * K + ktn + sg * 8, dst);
  };
  auto stB = [&](int nh, int j){   // stage B half nh, part j (32 rows)
    int hh = j * 8 + w;
    int row0 = (hh >> 2) * 64 + nh * 32 + (hh & 3) * 8;
    bf16* dst = nbuf + ABUF + row0 * 64;
    gload16(Bt + (size_t)(colB0 + row0 + srow) * K + ktn + sg * 8, dst);
  };
  auto stageAll = [&](){
    if (BMQ == 4){ stA(0); stA(2); stB(0,0); stB(0,1); stB(1,0); stB(1,1); stA(1); stA(3); }
    else         { stA(0); stA(1); stB(0,0); stB(0,1); stB(1,0); stB(1,1); }
  };

  const int NT = K >> 6;

  // prologue: stage tile 0, drain, barrier
  stageAll();
  asm volatile("s_waitcnt vmcnt(0)" ::: "memory");
  __builtin_amdgcn_sched_barrier(0);
  __builtin_amdgcn_s_barrier();
  __builtin_amdgcn_sched_barrier(0);

  bf16x8 af[4][2];        // current A half
  bf16x8 bfr[2][2][2];    // both B halves, live across the K-tile

#define RDA(MH)                                                               \
  _Pragma("unroll")                                                           \
  for (int fr = 0; fr < 4; ++fr)                                              \
    _Pragma("unroll")                                                         \
    for (int kk = 0; kk < 2; ++kk){                                           \
      int row = wr * (BM / 2) + (MH) * 64 + fr * 16 + lr;                     \
      af[fr][kk] = *(const bf16x8*)&Abuf[row * 64 +                           \
                     (((kk * 4 + lg) ^ (lr & 7)) << 3)];                      \
    }
#define RDB(NH)                                                               \
  _Pragma("unroll")                                                           \
  for (int fc = 0; fc < 2; ++fc)                                              \
    _Pragma("unroll")                                                         \
    for (int kk = 0; kk < 2; ++kk){                                           \
      int row = wc * 64 + (NH) * 32 + fc * 16 + lr;                           \
      bfr[NH][fc][kk] = *(const bf16x8*)&Bbuf[row * 64 +                      \
                     (((kk * 4 + lg) ^ (lr & 7)) << 3)];                      \
    }
#define MM(MH, NH)                                                            \
  __builtin_amdgcn_s_setprio(1);                                              \
  _Pragma("unroll")                                                           \
  for (int fr = 0; fr < 4; ++fr)                                              \
    _Pragma("unroll")                                                         \
    for (int fc = 0; fc < 2; ++fc)                                            \
      _Pragma("unroll")                                                       \
      for (int kk = 0; kk < 2; ++kk)                                          \
        acc[(MH) * 4 + fr][(NH) * 2 + fc] =                                   \
            mfma16(af[fr][kk], bfr[NH][fc][kk], acc[(MH) * 4 + fr][(NH) * 2 + fc]); \
  __builtin_amdgcn_s_setprio(0);

  for (int T = 0; T < NT; ++T){
    const bf16* Abuf = lds + (size_t)(T & 1) * BUFE;
    const bf16* Bbuf = Abuf + ABUF;
    nbuf = lds + (size_t)((T + 1) & 1) * BUFE;
    ktn  = (T + 1) << 6;
    const bool more = (T + 1 < NT);

    // stage ALL of tile T+1 up front: maximum vmcnt window (one full tile)
    if (more) stageAll();

    // compute tile T: ds_reads + MFMA, compiler-scheduled lgkm waits,
    // no mid-tile barriers (reads and stage-writes hit disjoint buffers)
    RDA(0); RDB(0);
    MM(0, 0);
    RDB(1);
    MM(0, 1);
    if (BMQ == 4){
      RDA(1);
      MM(1, 0);
      MM(1, 1);
    }

    if (more){
      asm volatile("s_waitcnt vmcnt(0)" ::: "memory");
      __builtin_amdgcn_sched_barrier(0);
      __builtin_amdgcn_s_barrier();
      __builtin_amdgcn_sched_barrier(0);
    }
  }
#undef RDA
#undef RDB
#undef MM

  // epilogue: acc[mi][ni], mi = MH*4+fr, ni = NH*2+fc
  const size_t crow = (size_t)rowA0 + wr * (BM / 2);
  const size_t ccol = (size_t)colB0 + wc * 64;
#pragma unroll
  for (int mi = 0; mi < MHN * 4; ++mi){
#pragma unroll
    for (int ni = 0; ni < 4; ++ni){
      size_t r0 = crow + (mi >> 2) * 64 + (mi & 3) * 16 + lg * 4;
      size_t c  = ccol + (ni >> 1) * 32 + (ni & 1) * 16 + lr;
#pragma unroll
      for (int i = 0; i < 4; ++i){
        size_t r = r0 + i;
        float v = acc[mi][ni][i];
        if (EPI == 0){
          ((bf16*)Cout)[r * (size_t)N + c] = (bf16)v;
        } else if (EPI == 1){
          v += bias[c];
          v = 0.5f * v * (1.0f + erff(v * 0.70710678118654752f));
          ((bf16*)Cout)[r * (size_t)N + c] = (bf16)v;
        } else {
          v += bias[c] + res[r * (size_t)N + c];
          ((float*)Cout)[r * (size_t)N + c] = v;
        }
      }
    }
  }
}

// ---------------- Flash attention: qkv bf16 [16384,2304] -> y bf16 [16384,768] ----------------
__global__ __launch_bounds__(256)
void attn_kernel(const bf16* __restrict__ qkv, bf16* __restrict__ y)
{
  int bid = blockIdx.x;
  int qt  = bid & 7;
  int bsh = bid >> 3;
  int h = bsh % 12;
  int R = bsh / 12;
  size_t rowbase = (size_t)R * 512;
  int tid = threadIdx.x, w = tid >> 6, l = tid & 63;
  int lr = l & 15, lg = l >> 4;

  __shared__ bf16 Kl[64 * 64];
  __shared__ bf16 Vt[64 * 64];
  __shared__ bf16 Pl[4][16 * 64];

  int q0 = qt * 64 + w * 16;
  bf16x8 qf[2];
#pragma unroll
  for (int ks = 0; ks < 2; ++ks)
    qf[ks] = *(const bf16x8*)&qkv[(rowbase + q0 + lr) * 2304 + h * 64 + ks * 32 + lg * 8];

  float mi[4], li[4];
  f32x4 oa[4];
#pragma unroll
  for (int i = 0; i < 4; ++i){ mi[i] = -1e30f; li[i] = 0.f; }
#pragma unroll
  for (int dt = 0; dt < 4; ++dt) oa[dt] = f32x4{0.f, 0.f, 0.f, 0.f};

  for (int c = 0; c < 8; ++c){
    __syncthreads();
    size_t tokbase = rowbase + c * 64;
#pragma unroll
    for (int it = 0; it < 2; ++it){
      int idx = it * 256 + tid;
      int t  = idx >> 3;
      int c8 = idx & 7;
      bf16x8 kv = *(const bf16x8*)&qkv[(tokbase + t) * 2304 + 768 + h * 64 + c8 * 8];
      *(bf16x8*)&Kl[t * 64 + ((c8 ^ (t & 7)) * 8)] = kv;
      bf16x8 vv = *(const bf16x8*)&qkv[(tokbase + t) * 2304 + 1536 + h * 64 + c8 * 8];
#pragma unroll
      for (int j = 0; j < 8; ++j){
        int d = c8 * 8 + j;
        Vt[d * 64 + (((t >> 3) ^ (d & 7)) * 8) + (t & 7)] = vv[j];
      }
    }
    __syncthreads();

    f32x4 s[4];
#pragma unroll
    for (int tt = 0; tt < 4; ++tt){
      f32x4 a = f32x4{0.f, 0.f, 0.f, 0.f};
#pragma unroll
      for (int ks = 0; ks < 2; ++ks){
        int row = tt * 16 + lr;
        int c8 = ks * 4 + lg;
        bf16x8 kf = *(const bf16x8*)&Kl[row * 64 + ((c8 ^ (row & 7)) * 8)];
        a = mfma16(qf[ks], kf, a);
      }
      s[tt] = a * 0.125f;
    }

    float pr[4][4];
#pragma unroll
    for (int i = 0; i < 4; ++i){
      float rm = fmaxf(fmaxf(s[0][i], s[1][i]), fmaxf(s[2][i], s[3][i]));
#pragma unroll
      for (int mm = 1; mm < 16; mm <<= 1) rm = fmaxf(rm, __shfl_xor(rm, mm, 64));
      float mn = fmaxf(mi[i], rm);
      float corr = __expf(mi[i] - mn);
      float rs = 0.f;
#pragma unroll
      for (int tt = 0; tt < 4; ++tt){
        float p = __expf(s[tt][i] - mn);
        pr[tt][i] = p;
        rs += p;
      }
#pragma unroll
      for (int mm = 1; mm < 16; mm <<= 1) rs += __shfl_xor(rs, mm, 64);
      li[i] = li[i] * corr + rs;
#pragma unroll
      for (int dt = 0; dt < 4; ++dt) oa[dt][i] *= corr;
      mi[i] = mn;
    }

#pragma unroll
    for (int i = 0; i < 4; ++i){
      int qr = lg * 4 + i;
#pragma unroll
      for (int tt = 0; tt < 4; ++tt){
        int tok = tt * 16 + lr;
        Pl[w][qr * 64 + (((tok >> 3) ^ (qr & 7)) * 8) + (tok & 7)] = (bf16)pr[tt][i];
      }
    }
    __syncthreads();

#pragma unroll
    for (int ks = 0; ks < 2; ++ks){
      bf16x8 pf = *(const bf16x8*)&Pl[w][lr * 64 + (((ks * 4 + lg) ^ (lr & 7)) * 8)];
#pragma unroll
      for (int dt = 0; dt < 4; ++dt){
        int row = dt * 16 + lr;
        int c8 = ks * 4 + lg;
        bf16x8 vf = *(const bf16x8*)&Vt[row * 64 + ((c8 ^ (row & 7)) * 8)];
        oa[dt] = mfma16(pf, vf, oa[dt]);
      }
    }
  }

#pragma unroll
  for (int i = 0; i < 4; ++i){
    float inv = 1.0f / li[i];
    size_t r = rowbase + q0 + lg * 4 + i;
#pragma unroll
    for (int dt = 0; dt < 4; ++dt)
      y[r * 768 + h * 64 + dt * 16 + lr] = (bf16)(oa[dt][i] * inv);
  }
}

// ---------------- launcher ----------------
extern "C" void kernel_launch(void* const* d_in, const int* in_sizes, int n_in,
                              void* d_out, int out_size, void* d_ws, size_t ws_size,
                              hipStream_t stream)
{
  (void)in_sizes; (void)n_in; (void)out_size; (void)ws_size;
  const float* x    = (const float*)d_in[0];
  const float* g1   = (const float*)d_in[1];
  const float* b1   = (const float*)d_in[2];
  const float* Wqkv = (const float*)d_in[3];
  const float* Wp   = (const float*)d_in[4];
  const float* bp   = (const float*)d_in[5];
  const float* g2   = (const float*)d_in[6];
  const float* b2   = (const float*)d_in[7];
  const float* W1   = (const float*)d_in[8];
  const float* bm1  = (const float*)d_in[9];
  const float* W2   = (const float*)d_in[10];
  const float* bm2  = (const float*)d_in[11];
  float* out = (float*)d_out;

  hipFuncSetAttribute((const void*)gemm256<0,4>, hipFuncAttributeMaxDynamicSharedMemorySize, 131072);
  hipFuncSetAttribute((const void*)gemm256<1,4>, hipFuncAttributeMaxDynamicSharedMemorySize, 131072);
  hipFuncSetAttribute((const void*)gemm256<2,2>, hipFuncAttributeMaxDynamicSharedMemorySize, 98304);

  // ---- lifetime-aliased workspace layout (~140 MB peak) ----
  char* ws = (char*)d_ws;
  size_t off = 0;
  auto alloc = [&](size_t nbytes) -> void* {
    void* p = ws + off;
    off += (nbytes + 255) & ~(size_t)255;
    return p;
  };
  bf16* WqkvT = (bf16*)alloc((size_t)2304 * 768 * 2);
  bf16* WpT   = (bf16*)alloc((size_t)768 * 768 * 2);
  bf16* W1T   = (bf16*)alloc((size_t)3072 * 768 * 2);
  bf16* W2T   = (bf16*)alloc((size_t)768 * 3072 * 2);
  char* R1 = (char*)alloc((size_t)16384 * 768 * 2);
  char* R2 = (char*)alloc((size_t)16384 * 3072 * 2);
  bf16* h   = (bf16*)R1;
  bf16* yb  = (bf16*)R1;
  bf16* h2  = (bf16*)R1;
  bf16* qkv = (bf16*)R2;
  bf16* m1  = (bf16*)R2;
  float* x2 = out;

  transpose_cast<<<dim3(36, 12), dim3(256), 0, stream>>>(Wqkv, WqkvT, 768, 2304);
  transpose_cast<<<dim3(12, 12), dim3(256), 0, stream>>>(Wp,   WpT,   768, 768);
  transpose_cast<<<dim3(48, 12), dim3(256), 0, stream>>>(W1,   W1T,   768, 3072);
  transpose_cast<<<dim3(12, 48), dim3(256), 0, stream>>>(W2,   W2T,   3072, 768);

  // LN1: x -> h (bf16)
  ln_kernel<<<dim3(16384), dim3(256), 0, stream>>>(x, g1, b1, h);
  // QKV: 64 x 9 = 576 blocks
  gemm256<0,4><<<dim3(576), dim3(512), 131072, stream>>>(h, WqkvT, nullptr, nullptr,
                                                         (void*)qkv, 16384, 2304, 768);
  // attention
  attn_kernel<<<dim3(3072), dim3(256), 0, stream>>>(qkv, yb);
  // proj + bias + residual(x) -> x2 (f32, in d_out); 128 x 3 = 384 blocks
  gemm256<2,2><<<dim3(384), dim3(512), 98304, stream>>>(yb, WpT, bp, x,
                                                        (void*)x2, 16384, 768, 768);
  // LN2
  ln_kernel<<<dim3(16384), dim3(256), 0, stream>>>(x2, g2, b2, h2);
  // MLP1 + bias + exact gelu; 64 x 12 = 768 blocks
  gemm256<1,4><<<dim3(768), dim3(512), 131072, stream>>>(h2, W1T, bm1, nullptr,
                                                         (void*)m1, 16384, 3072, 768);
  // MLP2 + bias + residual(x2) -> out; 128 x 3 = 384 blocks
  gemm256<2,2><<<dim3(384), dim3(512), 98304, stream>>>(m1, W2T, bm2, x2,
                                                        (void*)out, 16384, 768, 3072);
}